// Round 8
// baseline (2653.643 us; speedup 1.0000x reference)
//
#include <hip/hip_runtime.h>
#include <stdint.h>
#include <stddef.h>

// Persistent 2-layer LSTM, V8: layer-specialized pipeline with V6 mechanics.
// 4 clusters x 32 batch rows; cluster = 32 L1-blocks + 32 L2-blocks (16 cols
// each); h1/h2 recurrences run concurrently on disjoint CUs, coupled via a
// 4-deep out1 ring. V6-proven staging granules/swizzle; bias in acc-init.
// B=128,T=512,D=128,H=512. Grid 256 x 256 threads, 1 block/CU (99KB LDS).

typedef __attribute__((ext_vector_type(8))) short short8;
typedef __attribute__((ext_vector_type(4))) float f32x4;
typedef unsigned long long u64;

#define DEV static __device__ __forceinline__
#define SCOPE_AGENT __HIP_MEMORY_SCOPE_AGENT

constexpr int TSEQ = 512;
constexpr int DIN  = 128;
constexpr int HDIM = 512;
constexpr int NCL  = 4;    // clusters
constexpr int BB   = 32;   // batch rows per cluster
constexpr int NL1  = 32;   // layer-1 blocks per cluster
constexpr int NL2  = 32;   // layer-2 blocks per cluster
constexpr int COLS = 16;   // h-cols per block

DEV unsigned short f2bf(float f) {
  unsigned u = __float_as_uint(f);
  u += 0x7fffu + ((u >> 16) & 1u);   // RNE
  return (unsigned short)(u >> 16);
}
DEV short8 pack8(float4 a, float4 b) {
  short8 r;
  r[0] = (short)f2bf(a.x); r[1] = (short)f2bf(a.y);
  r[2] = (short)f2bf(a.z); r[3] = (short)f2bf(a.w);
  r[4] = (short)f2bf(b.x); r[5] = (short)f2bf(b.y);
  r[6] = (short)f2bf(b.z); r[7] = (short)f2bf(b.w);
  return r;
}
DEV short8 mk8(u64 lo, u64 hi) {
  union { u64 q[2]; short8 v; } u;
  u.q[0] = lo; u.q[1] = hi; return u.v;
}
DEV f32x4 mfma16(short8 a, short8 b, f32x4 c) {
  return __builtin_amdgcn_mfma_f32_16x16x32_bf16(a, b, c, 0, 0, 0);
}
DEV float sigf(float v) { return 1.f / (1.f + __expf(-v)); }
DEV float tanh_(float v) {
  v = fminf(20.f, fmaxf(-20.f, v));
  float e = __expf(2.f * v);
  return (e - 1.f) / (e + 1.f);
}
// lanes 0..31 watch fA[lane]>=tgtA ; lanes 32..63 watch fB[lane-32]>=tgtB
DEV void pollAB(const unsigned* fA, unsigned tgtA,
                const unsigned* fB, unsigned tgtB, int lane) {
  const unsigned* fp = (lane < 32) ? (fA + lane) : (fB + (lane - 32));
  const unsigned tgt = (lane < 32) ? tgtA : tgtB;
  while (true) {
    unsigned v = __hip_atomic_load(fp, __ATOMIC_RELAXED, SCOPE_AGENT);
    if (__all((int)(v >= tgt))) break;
    __builtin_amdgcn_s_sleep(1);
  }
}

__global__ void zero_ws(unsigned* p, int n) {
  int i = blockIdx.x * 256 + threadIdx.x;
  if (i < n)
    __hip_atomic_store(p + i, 0u, __ATOMIC_RELAXED, SCOPE_AGENT);
}

// LDS slab swizzle on short-index: byte ^ ((row&15)<<4)
#define SWZ(row, idx) ((idx) ^ (((row) & 15) << 3))

__global__ __launch_bounds__(256, 1) void lstm_pipe2(
    const float* __restrict__ x,
    const float* __restrict__ Wih1, const float* __restrict__ Whh1,
    const float* __restrict__ bih1, const float* __restrict__ bhh1,
    const float* __restrict__ Wih2, const float* __restrict__ Whh2,
    const float* __restrict__ bih2, const float* __restrict__ bhh2,
    float* __restrict__ out,
    unsigned short* __restrict__ buf1,   // [4][NCL][BB][HDIM] bf16 h1/out1 ring
    unsigned short* __restrict__ buf2,   // [2][NCL][BB][HDIM] bf16 h2 ring
    unsigned* __restrict__ flags)        // [NCL][64]: A=0..31, B=32..63
{
  __shared__ union {
    struct { short xs[32 * DIN]; short h1s[32 * HDIM]; float red[8 * 16 * 66]; } l1;
    struct { short o1s[32 * HDIM]; short h2s[32 * HDIM]; float red[8 * 16 * 66]; } l2;
  } sm;

  const int tid  = threadIdx.x;
  const int lane = tid & 63;
  const int lm   = lane & 15;   // A row (within M-tile) / C col index
  const int lq   = lane >> 4;   // k-octet / C row group
  const int kq   = tid >> 6;    // wave = K-quarter

  const int bid     = blockIdx.x;
  const int cluster = bid & 3;
  const int sub     = bid >> 2;       // 0..63
  const int cb      = cluster * BB;
  unsigned* flagA = flags + cluster * 64;
  unsigned* flagB = flags + cluster * 64 + 32;
  const int pm = tid >> 4, pci = tid & 15;   // pickup (row-in-tile, col)

  if (sub < NL1) {
    // ================= LAYER-1 BLOCK: 16 cols at j*16 =================
    const int j = sub;
    short8 wf[4][5];   // [gate][K-step of this quarter] = 80 VGPR
    float binit[4];
    #pragma unroll
    for (int nt = 0; nt < 4; ++nt) {
      const int gr = nt * HDIM + j * COLS + lm;
      #pragma unroll
      for (int sl = 0; sl < 5; ++sl) {
        const int k0 = (kq * 5 + sl) * 32 + 8 * lq;   // 0..639
        const float* src = (k0 < DIN) ? (Wih1 + (size_t)gr * DIN + k0)
                                      : (Whh1 + (size_t)gr * HDIM + (k0 - DIN));
        wf[nt][sl] = pack8(*(const float4*)src, *(const float4*)(src + 4));
      }
      binit[nt] = (kq == 0) ? (bih1[gr] + bhh1[gr]) : 0.f;
    }
    float c1p[2] = {0.f, 0.f};

    for (int it = 0; it < TSEQ; ++it) {
      // x loads (independent; issue before the poll)
      float4 xv[4];
      #pragma unroll
      for (int i = 0; i < 2; ++i) {
        const int g = i * 256 + tid, xrow = g >> 4, xseg = g & 15;
        const float* xp = x + ((size_t)(cb + xrow) * TSEQ + it) * DIN + xseg * 8;
        xv[2 * i] = *(const float4*)xp; xv[2 * i + 1] = *(const float4*)(xp + 4);
      }
      if (it > 0) {
        if (kq == 0)
          pollAB(flagA, (unsigned)it,
                 flagB, (it >= 3) ? (unsigned)(it - 3) : 0u, lane);
        __syncthreads();
      }
      // stage x_t
      #pragma unroll
      for (int i = 0; i < 2; ++i) {
        const int g = i * 256 + tid, xrow = g >> 4, xseg = g & 15;
        *(short8*)(&sm.l1.xs[SWZ(xrow, xrow * DIN + xseg * 8)]) =
            pack8(xv[2 * i], xv[2 * i + 1]);
      }
      // stage h1_{it-1} from slot (it-1)&3  (V6 granule pattern: 2-way-free)
      {
        const unsigned short* h1r =
            buf1 + (size_t)((((it + 3) & 3) * NCL + cluster) * BB) * HDIM;
        u64 t[16];
        #pragma unroll
        for (int i = 0; i < 8; ++i) {
          const int g = i * 256 + tid, row = g >> 6, kc = g & 63;
          const u64* s = (const u64*)(h1r + (size_t)row * HDIM + kc * 8);
          t[2 * i]     = __hip_atomic_load(s,     __ATOMIC_RELAXED, SCOPE_AGENT);
          t[2 * i + 1] = __hip_atomic_load(s + 1, __ATOMIC_RELAXED, SCOPE_AGENT);
        }
        #pragma unroll
        for (int i = 0; i < 8; ++i) {
          const int g = i * 256 + tid, row = g >> 6, kc = g & 63;
          *(short8*)(&sm.l1.h1s[SWZ(row, row * HDIM + kc * 8)]) =
              mk8(t[2 * i], t[2 * i + 1]);
        }
      }
      __syncthreads();
      // MFMA: 5 K-steps x 2 M-tiles x 4 gates = 40
      f32x4 acc[2][4];
      #pragma unroll
      for (int mt = 0; mt < 2; ++mt)
        #pragma unroll
        for (int nt = 0; nt < 4; ++nt)
          acc[mt][nt] = f32x4{binit[nt], binit[nt], binit[nt], binit[nt]};
      #pragma unroll
      for (int sl = 0; sl < 5; ++sl) {
        const int s = kq * 5 + sl;   // K = [x(4) | h1(16)]
        short8 a0, a1;
        if (s < 4) {  // only kq==0
          a0 = *(const short8*)(&sm.l1.xs[SWZ(lm, lm * DIN + s * 32 + 8 * lq)]);
          a1 = *(const short8*)(&sm.l1.xs[SWZ(lm + 16, (lm + 16) * DIN + s * 32 + 8 * lq)]);
        } else {
          const int off = (s - 4) * 32 + 8 * lq;
          a0 = *(const short8*)(&sm.l1.h1s[SWZ(lm, lm * HDIM + off)]);
          a1 = *(const short8*)(&sm.l1.h1s[SWZ(lm + 16, (lm + 16) * HDIM + off)]);
        }
        #pragma unroll
        for (int nt = 0; nt < 4; ++nt) {
          acc[0][nt] = mfma16(a0, wf[nt][sl], acc[0][nt]);
          acc[1][nt] = mfma16(a1, wf[nt][sl], acc[1][nt]);
        }
      }
      #pragma unroll
      for (int mt = 0; mt < 2; ++mt)
        #pragma unroll
        for (int nt = 0; nt < 4; ++nt)
          #pragma unroll
          for (int r = 0; r < 4; ++r)
            sm.l1.red[((kq * 2 + mt) * 16 + lq * 4 + r) * 66 + nt * 16 + lm] =
                acc[mt][nt][r];
      __syncthreads();
      // pickup: rows pm and pm+16, col j*16+pci; publish to slot it&3
      unsigned short* wp =
          buf1 + (size_t)(((it & 3) * NCL + cluster) * BB) * HDIM;
      #pragma unroll
      for (int p = 0; p < 2; ++p) {
        const int row = p * 16 + pm;
        float pg[4];
        #pragma unroll
        for (int g = 0; g < 4; ++g) {
          float v = 0.f;
          #pragma unroll
          for (int q = 0; q < 4; ++q)
            v += sm.l1.red[((q * 2 + p) * 16 + pm) * 66 + g * 16 + pci];
          pg[g] = v;
        }
        const float i_ = sigf(pg[0]), f_ = sigf(pg[1]);
        const float g_ = tanh_(pg[2]), o_ = sigf(pg[3]);
        c1p[p] = f_ * c1p[p] + i_ * g_;
        const float h1v = o_ * tanh_(c1p[p]);
        __hip_atomic_store(&wp[(size_t)row * HDIM + j * COLS + pci], f2bf(h1v),
                           __ATOMIC_RELAXED, SCOPE_AGENT);
      }
      __syncthreads();   // drains vmcnt: publishes complete
      if (tid == 0)
        __hip_atomic_store(flagA + j, (unsigned)(it + 1),
                           __ATOMIC_RELAXED, SCOPE_AGENT);
    }
  } else {
    // ================= LAYER-2 BLOCK: 16 cols at j2*16 =================
    const int j2 = sub - NL1;
    short8 wf[4][8];   // [gate][K-step of this quarter] = 128 VGPR
    float binit[4];
    #pragma unroll
    for (int nt = 0; nt < 4; ++nt) {
      const int gr = nt * HDIM + j2 * COLS + lm;
      #pragma unroll
      for (int sl = 0; sl < 8; ++sl) {
        const int k0 = (kq * 8 + sl) * 32 + 8 * lq;   // 0..1023
        const float* src = (k0 < HDIM) ? (Wih2 + (size_t)gr * HDIM + k0)
                                       : (Whh2 + (size_t)gr * HDIM + (k0 - HDIM));
        wf[nt][sl] = pack8(*(const float4*)src, *(const float4*)(src + 4));
      }
      binit[nt] = (kq == 0) ? (bih2[gr] + bhh2[gr]) : 0.f;
    }
    float c2p[2] = {0.f, 0.f};

    for (int t2 = 0; t2 < TSEQ; ++t2) {
      if (kq == 0)
        pollAB(flagA, (unsigned)(t2 + 1), flagB, (unsigned)t2, lane);
      __syncthreads();
      // stage out1_{t2} (slot t2&3) and h2_{t2-1} (slot (t2+1)&1)
      {
        const unsigned short* o1r =
            buf1 + (size_t)(((t2 & 3) * NCL + cluster) * BB) * HDIM;
        const unsigned short* h2r =
            buf2 + (size_t)((((t2 + 1) & 1) * NCL + cluster) * BB) * HDIM;
        u64 t[32];
        #pragma unroll
        for (int i = 0; i < 8; ++i) {
          const int g = i * 256 + tid, row = g >> 6, kc = g & 63;
          const u64* s1 = (const u64*)(o1r + (size_t)row * HDIM + kc * 8);
          const u64* s2 = (const u64*)(h2r + (size_t)row * HDIM + kc * 8);
          t[2 * i]      = __hip_atomic_load(s1,     __ATOMIC_RELAXED, SCOPE_AGENT);
          t[2 * i + 1]  = __hip_atomic_load(s1 + 1, __ATOMIC_RELAXED, SCOPE_AGENT);
          t[16 + 2 * i] = __hip_atomic_load(s2,     __ATOMIC_RELAXED, SCOPE_AGENT);
          t[17 + 2 * i] = __hip_atomic_load(s2 + 1, __ATOMIC_RELAXED, SCOPE_AGENT);
        }
        #pragma unroll
        for (int i = 0; i < 8; ++i) {
          const int g = i * 256 + tid, row = g >> 6, kc = g & 63;
          *(short8*)(&sm.l2.o1s[SWZ(row, row * HDIM + kc * 8)]) =
              mk8(t[2 * i], t[2 * i + 1]);
          *(short8*)(&sm.l2.h2s[SWZ(row, row * HDIM + kc * 8)]) =
              mk8(t[16 + 2 * i], t[17 + 2 * i]);
        }
      }
      __syncthreads();
      // MFMA: 8 K-steps x 2 M-tiles x 4 gates = 64 ; slab constant per wave
      f32x4 acc[2][4];
      #pragma unroll
      for (int mt = 0; mt < 2; ++mt)
        #pragma unroll
        for (int nt = 0; nt < 4; ++nt)
          acc[mt][nt] = f32x4{binit[nt], binit[nt], binit[nt], binit[nt]};
      const short* slab = (kq < 2) ? sm.l2.o1s : sm.l2.h2s;
      #pragma unroll
      for (int sl = 0; sl < 8; ++sl) {
        const int off = ((kq & 1) * 8 + sl) * 32 + 8 * lq;   // within 512-K half
        const short8 a0 = *(const short8*)(&slab[SWZ(lm, lm * HDIM + off)]);
        const short8 a1 = *(const short8*)(&slab[SWZ(lm + 16, (lm + 16) * HDIM + off)]);
        #pragma unroll
        for (int nt = 0; nt < 4; ++nt) {
          acc[0][nt] = mfma16(a0, wf[nt][sl], acc[0][nt]);
          acc[1][nt] = mfma16(a1, wf[nt][sl], acc[1][nt]);
        }
      }
      #pragma unroll
      for (int mt = 0; mt < 2; ++mt)
        #pragma unroll
        for (int nt = 0; nt < 4; ++nt)
          #pragma unroll
          for (int r = 0; r < 4; ++r)
            sm.l2.red[((kq * 2 + mt) * 16 + lq * 4 + r) * 66 + nt * 16 + lm] =
                acc[mt][nt][r];
      __syncthreads();
      // pickup: rows pm, pm+16; publish h2 (t2<511) or final out (t2=511)
      #pragma unroll
      for (int p = 0; p < 2; ++p) {
        const int row = p * 16 + pm;
        float pg[4];
        #pragma unroll
        for (int g = 0; g < 4; ++g) {
          float v = 0.f;
          #pragma unroll
          for (int q = 0; q < 4; ++q)
            v += sm.l2.red[((q * 2 + p) * 16 + pm) * 66 + g * 16 + pci];
          pg[g] = v;
        }
        const float i_ = sigf(pg[0]), f_ = sigf(pg[1]);
        const float g_ = tanh_(pg[2]), o_ = sigf(pg[3]);
        c2p[p] = f_ * c2p[p] + i_ * g_;
        const float h2v = o_ * tanh_(c2p[p]);
        if (t2 < TSEQ - 1) {
          unsigned short* wp =
              buf2 + (size_t)(((t2 & 1) * NCL + cluster) * BB) * HDIM;
          __hip_atomic_store(&wp[(size_t)row * HDIM + j2 * COLS + pci], f2bf(h2v),
                             __ATOMIC_RELAXED, SCOPE_AGENT);
        } else {
          const int b = cb + row;
          out[(size_t)b * HDIM + j2 * COLS + pci] = h2v;
          out[(size_t)128 * HDIM + (size_t)b * HDIM + j2 * COLS + pci] = c2p[p];
        }
      }
      __syncthreads();   // drains vmcnt: publishes complete
      if (tid == 0 && t2 < TSEQ - 1)
        __hip_atomic_store(flagB + j2, (unsigned)(t2 + 1),
                           __ATOMIC_RELAXED, SCOPE_AGENT);
    }
  }
}

extern "C" void kernel_launch(void* const* d_in, const int* in_sizes, int n_in,
                              void* d_out, int out_size, void* d_ws, size_t ws_size,
                              hipStream_t stream) {
  const float* x    = (const float*)d_in[0];
  const float* Wih1 = (const float*)d_in[1];
  const float* Whh1 = (const float*)d_in[2];
  const float* bih1 = (const float*)d_in[3];
  const float* bhh1 = (const float*)d_in[4];
  const float* Wih2 = (const float*)d_in[5];
  const float* Whh2 = (const float*)d_in[6];
  const float* bih2 = (const float*)d_in[7];
  const float* bhh2 = (const float*)d_in[8];
  float* out = (float*)d_out;

  const size_t buf1Elems = (size_t)4 * NCL * BB * HDIM;   // 262144 ushorts
  const size_t buf2Elems = (size_t)2 * NCL * BB * HDIM;   // 131072 ushorts
  unsigned short* buf1 = (unsigned short*)d_ws;
  unsigned short* buf2 = buf1 + buf1Elems;
  unsigned* flags = (unsigned*)(buf2 + buf2Elems);

  const int nzero = (int)(((buf1Elems + buf2Elems) * 2 + NCL * 64 * 4) / 4);
  zero_ws<<<(nzero + 255) / 256, 256, 0, stream>>>((unsigned*)d_ws, nzero);
  lstm_pipe2<<<(NL1 + NL2) * NCL, 256, 0, stream>>>(
      x, Wih1, Whh1, bih1, bhh1, Wih2, Whh2, bih2, bhh2,
      out, buf1, buf2, flags);
}

// Round 10
// 1981.860 us; speedup vs baseline: 1.3390x; 1.3390x over previous
//
#include <hip/hip_runtime.h>
#include <stdint.h>
#include <stddef.h>

// Persistent 2-layer LSTM, V10: V6 structure + software-pipelined schedule.
// L2 lags 3 steps (4-deep out1 ring): x and out1 loads issue BEFORE the poll
// (RT hides under the wait); after the poll the L1 chain runs at minimum
// latency (h1 stage -> MFMA -> pickup -> publish -> flagA), and the whole L2
// pipeline runs AFTER flagA, filling the flag-propagation window.
// All cross-block comm = __hip_atomic_* SCOPE_AGENT (the proven path).
// B=128,T=512,D=128,H=512. 8 clusters x 32 blocks; block owns 16 h-cols of
// both layers; 4 waves = 4 K-quarters; 1 block/CU (86KB LDS).

typedef __attribute__((ext_vector_type(8))) short short8;
typedef __attribute__((ext_vector_type(4))) float f32x4;
typedef unsigned long long u64;

#define DEV static __device__ __forceinline__
#define SCOPE_AGENT __HIP_MEMORY_SCOPE_AGENT

constexpr int TSEQ = 512;
constexpr int DIN  = 128;
constexpr int HDIM = 512;
constexpr int NCL  = 8;    // clusters (bid&7; heuristic, perf-only)
constexpr int BB   = 16;   // batch rows per cluster
constexpr int NJ   = 32;   // blocks per cluster
constexpr int COLS = 16;   // h-cols per block

DEV unsigned short f2bf(float f) {
  unsigned u = __float_as_uint(f);
  u += 0x7fffu + ((u >> 16) & 1u);   // RNE
  return (unsigned short)(u >> 16);
}
DEV short8 pack8(float4 a, float4 b) {
  short8 r;
  r[0] = (short)f2bf(a.x); r[1] = (short)f2bf(a.y);
  r[2] = (short)f2bf(a.z); r[3] = (short)f2bf(a.w);
  r[4] = (short)f2bf(b.x); r[5] = (short)f2bf(b.y);
  r[6] = (short)f2bf(b.z); r[7] = (short)f2bf(b.w);
  return r;
}
DEV short8 mk8(u64 lo, u64 hi) {
  union { u64 q[2]; short8 v; } u;
  u.q[0] = lo; u.q[1] = hi; return u.v;
}
DEV f32x4 mfma16(short8 a, short8 b, f32x4 c) {
  return __builtin_amdgcn_mfma_f32_16x16x32_bf16(a, b, c, 0, 0, 0);
}
DEV float sigf(float v) { return 1.f / (1.f + __expf(-v)); }
DEV float tanh_(float v) {
  v = fminf(20.f, fmaxf(-20.f, v));
  float e = __expf(2.f * v);
  return (e - 1.f) / (e + 1.f);
}

__global__ void zero_ws(unsigned* p, int n) {
  int i = blockIdx.x * 256 + threadIdx.x;
  if (i < n)
    __hip_atomic_store(p + i, 0u, __ATOMIC_RELAXED, SCOPE_AGENT);
}

// LDS slab swizzle on short-index: byte ^ ((row&15)<<4)
#define SWZ(row, idx) ((idx) ^ (((row) & 15) << 3))

__global__ __launch_bounds__(256, 1) void lstm_persist(
    const float* __restrict__ x,
    const float* __restrict__ Wih1, const float* __restrict__ Whh1,
    const float* __restrict__ bih1, const float* __restrict__ bhh1,
    const float* __restrict__ Wih2, const float* __restrict__ Whh2,
    const float* __restrict__ bih2, const float* __restrict__ bhh2,
    float* __restrict__ out,
    unsigned short* __restrict__ buf1,   // [4][NCL][BB][HDIM] bf16 h1/out1 ring
    unsigned short* __restrict__ buf2,   // [2][NCL][BB][HDIM] bf16 h2 ring
    unsigned* __restrict__ flags)        // [NCL][64]: A=0..31, B=32..63
{
  __shared__ short xs [16 * DIN];    // 4KB   x_t slab (bf16, swizzled)
  __shared__ short h1s[16 * HDIM];   // 16KB  h1_{it-1}
  __shared__ short o1s[16 * HDIM];   // 16KB  out1_{it-3}
  __shared__ short h2s[16 * HDIM];   // 16KB  h2_{it-4}
  __shared__ float red1[4 * 16 * 66];
  __shared__ float red2[4 * 16 * 66];
  __shared__ float bias1s[64], bias2s[64];

  const int tid  = threadIdx.x;
  const int lane = tid & 63;
  const int lm   = lane & 15;   // A row (batch row) / C col index
  const int lq   = lane >> 4;   // k-octet / C row group
  const int kq   = tid >> 6;    // wave = K-quarter

  const int bid     = blockIdx.x;
  const int cluster = bid & 7;
  const int j       = bid >> 3;       // 0..31 col-group within cluster
  const int cb      = cluster * BB;   // global batch base
  unsigned* flagA = flags + cluster * 64;        // flagA=k <=> h1_{k-1} published
  unsigned* flagB = flags + cluster * 64 + NJ;   // flagB=k <=> h2_{k-3} published

  // ---- persistent register weights: B-fragments, n = lane&15 -> gate row ----
  short8 wf1[4][5];   // layer1: K=640 -> 20 K-steps, 5 per wave, x4 gates
  short8 wf2[4][8];   // layer2: K=1024 -> 32 K-steps, 8 per wave, x4 gates
  #pragma unroll
  for (int g = 0; g < 4; ++g) {
    const int gr = g * HDIM + j * COLS + lm;
    #pragma unroll
    for (int sl = 0; sl < 5; ++sl) {
      const int k0 = (kq * 5 + sl) * 32 + 8 * lq;          // 0..639
      const float* src = (k0 < DIN) ? (Wih1 + (size_t)gr * DIN + k0)
                                    : (Whh1 + (size_t)gr * HDIM + (k0 - DIN));
      wf1[g][sl] = pack8(*(const float4*)src, *(const float4*)(src + 4));
    }
    #pragma unroll
    for (int sl = 0; sl < 8; ++sl) {
      const int k0 = (kq * 8 + sl) * 32 + 8 * lq;          // 0..1023
      const float* src = (k0 < HDIM) ? (Wih2 + (size_t)gr * HDIM + k0)
                                     : (Whh2 + (size_t)gr * HDIM + (k0 - HDIM));
      wf2[g][sl] = pack8(*(const float4*)src, *(const float4*)(src + 4));
    }
  }
  if (tid < 64) {
    const int g = tid >> 4, nn = tid & 15;
    const int gr = g * HDIM + j * COLS + nn;
    bias1s[tid] = bih1[gr] + bhh1[gr];
    bias2s[tid] = bih2[gr] + bhh2[gr];
  }

  // pickup: thread = (batch row pm, col pnn); owns c1,c2 across all steps
  const int pm = tid >> 4, pnn = tid & 15;
  float c1 = 0.f, c2 = 0.f;

  for (int it = 0; it <= TSEQ + 2; ++it) {
    const bool l1 = (it < TSEQ);
    const bool l2 = (it >= 3);          // processes t2 = it-3
    const int  t2 = it - 3;

    // ---- pre-poll loads (deps confirmed by LAST step's poll) ----
    float4 xa, xb;
    if (l1) {
      const int row = tid >> 4, kc = tid & 15;
      const float* xp = x + ((size_t)(cb + row) * TSEQ + it) * DIN + kc * 8;
      xa = *(const float4*)xp; xb = *(const float4*)(xp + 4);
    }
    u64 o1t[8];
    if (l2) {   // out1_{it-3} from ring slot (it-3)&3
      const unsigned short* o1r =
          buf1 + (size_t)(((t2 & 3) * NCL + cluster) * BB) * HDIM;
      #pragma unroll
      for (int ci = 0; ci < 4; ++ci) {
        const int g = ci * 256 + tid, row = g >> 6, kc = g & 63;
        const u64* s = (const u64*)(o1r + (size_t)row * HDIM + kc * 8);
        o1t[2 * ci]     = __hip_atomic_load(s,     __ATOMIC_RELAXED, SCOPE_AGENT);
        o1t[2 * ci + 1] = __hip_atomic_load(s + 1, __ATOMIC_RELAXED, SCOPE_AGENT);
      }
    }

    // ---- poll: A >= min(it,TSEQ) (h1_{it-1}); B >= it-1 (h2_{it-4}) ----
    if (it > 0) {
      if (kq == 0) {
        const unsigned tgtA = (unsigned)(l1 ? it : TSEQ);
        const unsigned tgtB = (it >= 4) ? (unsigned)(it - 1) : 0u;
        const unsigned tgt  = (lane < NJ) ? tgtA : tgtB;
        const unsigned* fl  = flagA + lane;   // lanes 0..31: A, 32..63: B
        while (true) {
          unsigned v = __hip_atomic_load(fl, __ATOMIC_RELAXED, SCOPE_AGENT);
          if (__all((int)(v >= tgt))) break;
          __builtin_amdgcn_s_sleep(1);
        }
      }
      __syncthreads();
    }

    // ---- write pre-loaded x/out1 to LDS; issue + write h1/h2 ----
    if (l1) {
      const int row = tid >> 4, kc = tid & 15;
      *(short8*)(&xs[SWZ(row, row * DIN + kc * 8)]) = pack8(xa, xb);
    }
    if (l2) {
      #pragma unroll
      for (int ci = 0; ci < 4; ++ci) {
        const int g = ci * 256 + tid, row = g >> 6, kc = g & 63;
        *(short8*)(&o1s[SWZ(row, row * HDIM + kc * 8)]) =
            mk8(o1t[2 * ci], o1t[2 * ci + 1]);
      }
    }
    {
      u64 h1t[8], h2t[8];
      const unsigned short* h1r =
          buf1 + (size_t)((((it + 3) & 3) * NCL + cluster) * BB) * HDIM;  // slot (it-1)&3
      const unsigned short* h2r =
          buf2 + (size_t)(((it & 1) * NCL + cluster) * BB) * HDIM;        // slot (it-4)&1
      if (l1) {
        #pragma unroll
        for (int ci = 0; ci < 4; ++ci) {
          const int g = ci * 256 + tid, row = g >> 6, kc = g & 63;
          const u64* s = (const u64*)(h1r + (size_t)row * HDIM + kc * 8);
          h1t[2 * ci]     = __hip_atomic_load(s,     __ATOMIC_RELAXED, SCOPE_AGENT);
          h1t[2 * ci + 1] = __hip_atomic_load(s + 1, __ATOMIC_RELAXED, SCOPE_AGENT);
        }
      }
      if (l2) {
        #pragma unroll
        for (int ci = 0; ci < 4; ++ci) {
          const int g = ci * 256 + tid, row = g >> 6, kc = g & 63;
          const u64* s = (const u64*)(h2r + (size_t)row * HDIM + kc * 8);
          h2t[2 * ci]     = __hip_atomic_load(s,     __ATOMIC_RELAXED, SCOPE_AGENT);
          h2t[2 * ci + 1] = __hip_atomic_load(s + 1, __ATOMIC_RELAXED, SCOPE_AGENT);
        }
      }
      if (l1) {
        #pragma unroll
        for (int ci = 0; ci < 4; ++ci) {
          const int g = ci * 256 + tid, row = g >> 6, kc = g & 63;
          *(short8*)(&h1s[SWZ(row, row * HDIM + kc * 8)]) =
              mk8(h1t[2 * ci], h1t[2 * ci + 1]);
        }
      }
      if (l2) {
        #pragma unroll
        for (int ci = 0; ci < 4; ++ci) {
          const int g = ci * 256 + tid, row = g >> 6, kc = g & 63;
          *(short8*)(&h2s[SWZ(row, row * HDIM + kc * 8)]) =
              mk8(h2t[2 * ci], h2t[2 * ci + 1]);
        }
      }
    }
    __syncthreads();

    // ================= LAYER 1 (the h1 recurrence critical chain) ==========
    if (l1) {
      f32x4 z = {0.f, 0.f, 0.f, 0.f};
      f32x4 acc1[4] = {z, z, z, z};
      #pragma unroll
      for (int sl = 0; sl < 5; ++sl) {
        const int s = kq * 5 + sl;       // K = [x(4) | h1(16)] K-steps
        short8 a;
        if (s < 4)   // only kq==0
          a = *(const short8*)(&xs[SWZ(lm, lm * DIN + s * 32 + 8 * lq)]);
        else
          a = *(const short8*)(&h1s[SWZ(lm, lm * HDIM + (s - 4) * 32 + 8 * lq)]);
        #pragma unroll
        for (int g = 0; g < 4; ++g) acc1[g] = mfma16(a, wf1[g][sl], acc1[g]);
      }
      #pragma unroll
      for (int g = 0; g < 4; ++g)
        #pragma unroll
        for (int r = 0; r < 4; ++r)
          red1[(kq * 16 + lq * 4 + r) * 66 + g * 16 + lm] = acc1[g][r];
    }
    __syncthreads();
    if (l1) {
      float p[4];
      #pragma unroll
      for (int g = 0; g < 4; ++g) {
        float v = bias1s[g * 16 + pnn];
        #pragma unroll
        for (int q = 0; q < 4; ++q) v += red1[(q * 16 + pm) * 66 + g * 16 + pnn];
        p[g] = v;
      }
      const float i_ = sigf(p[0]), f_ = sigf(p[1]);
      const float g_ = tanh_(p[2]), o_ = sigf(p[3]);
      c1 = f_ * c1 + i_ * g_;
      const float h1v = o_ * tanh_(c1);
      unsigned short* wp =
          buf1 + (size_t)(((it & 3) * NCL + cluster) * BB) * HDIM;  // slot it&3
      __hip_atomic_store(&wp[pm * HDIM + j * COLS + pnn], f2bf(h1v),
                         __ATOMIC_RELAXED, SCOPE_AGENT);
    }
    __syncthreads();   // drains vmcnt: h1 publishes complete
    if (tid == 0 && l1)
      __hip_atomic_store(flagA + j, (unsigned)(it + 1),
                         __ATOMIC_RELAXED, SCOPE_AGENT);

    // ================= LAYER 2 (lag-3; fills flagA propagation window) =====
    if (l2) {
      f32x4 z = {0.f, 0.f, 0.f, 0.f};
      f32x4 acc2[4] = {z, z, z, z};
      #pragma unroll
      for (int sl = 0; sl < 8; ++sl) {
        const int s2 = kq * 8 + sl;      // K = [out1(16) | h2(16)] K-steps
        short8 a;
        if (s2 < 16)
          a = *(const short8*)(&o1s[SWZ(lm, lm * HDIM + s2 * 32 + 8 * lq)]);
        else
          a = *(const short8*)(&h2s[SWZ(lm, lm * HDIM + (s2 - 16) * 32 + 8 * lq)]);
        #pragma unroll
        for (int g = 0; g < 4; ++g) acc2[g] = mfma16(a, wf2[g][sl], acc2[g]);
      }
      #pragma unroll
      for (int g = 0; g < 4; ++g)
        #pragma unroll
        for (int r = 0; r < 4; ++r)
          red2[(kq * 16 + lq * 4 + r) * 66 + g * 16 + lm] = acc2[g][r];
    }
    __syncthreads();
    if (l2) {
      float p[4];
      #pragma unroll
      for (int g = 0; g < 4; ++g) {
        float v = bias2s[g * 16 + pnn];
        #pragma unroll
        for (int q = 0; q < 4; ++q) v += red2[(q * 16 + pm) * 66 + g * 16 + pnn];
        p[g] = v;
      }
      const float i_ = sigf(p[0]), f_ = sigf(p[1]);
      const float g_ = tanh_(p[2]), o_ = sigf(p[3]);
      c2 = f_ * c2 + i_ * g_;
      const float h2v = o_ * tanh_(c2);
      if (t2 < TSEQ - 1) {
        unsigned short* wp =
            buf2 + (size_t)((((it + 1) & 1) * NCL + cluster) * BB) * HDIM; // slot (it-3)&1
        __hip_atomic_store(&wp[pm * HDIM + j * COLS + pnn], f2bf(h2v),
                           __ATOMIC_RELAXED, SCOPE_AGENT);
      } else {
        const int b = cb + pm;                       // final states (t2 = 511)
        out[(size_t)b * HDIM + j * COLS + pnn] = h2v;
        out[(size_t)128 * HDIM + (size_t)b * HDIM + j * COLS + pnn] = c2;
      }
    }
    __syncthreads();   // drains vmcnt: h2 publishes complete
    if (tid == 0 && l2)
      __hip_atomic_store(flagB + j, (unsigned)it,
                         __ATOMIC_RELAXED, SCOPE_AGENT);
  }
}

extern "C" void kernel_launch(void* const* d_in, const int* in_sizes, int n_in,
                              void* d_out, int out_size, void* d_ws, size_t ws_size,
                              hipStream_t stream) {
  const float* x    = (const float*)d_in[0];
  const float* Wih1 = (const float*)d_in[1];
  const float* Whh1 = (const float*)d_in[2];
  const float* bih1 = (const float*)d_in[3];
  const float* bhh1 = (const float*)d_in[4];
  const float* Wih2 = (const float*)d_in[5];
  const float* Whh2 = (const float*)d_in[6];
  const float* bih2 = (const float*)d_in[7];
  const float* bhh2 = (const float*)d_in[8];
  float* out = (float*)d_out;

  const size_t buf1Elems = (size_t)4 * NCL * BB * HDIM;   // 262144 ushorts
  const size_t buf2Elems = (size_t)2 * NCL * BB * HDIM;   // 131072 ushorts
  unsigned short* buf1 = (unsigned short*)d_ws;
  unsigned short* buf2 = buf1 + buf1Elems;
  unsigned* flags = (unsigned*)(buf2 + buf2Elems);

  const int nzero = (int)(((buf1Elems + buf2Elems) * 2 + NCL * 64 * 4) / 4);
  zero_ws<<<(nzero + 255) / 256, 256, 0, stream>>>((unsigned*)d_ws, nzero);
  lstm_persist<<<256, 256, 0, stream>>>(x, Wih1, Whh1, bih1, bhh1,
                                        Wih2, Whh2, bih2, bhh2,
                                        out, buf1, buf2, flags);
}